// Round 1
// baseline (309.843 us; speedup 1.0000x reference)
//
#include <hip/hip_runtime.h>

typedef __bf16 bf16;
typedef _Float16 f16;
typedef __bf16 bf16x8 __attribute__((ext_vector_type(8)));
typedef _Float16 f16x8 __attribute__((ext_vector_type(8)));
typedef float  f32x4  __attribute__((ext_vector_type(4)));

#define B_  8
#define N_  2048
#define F_  256
#define NTOK (B_ * N_)
// WhT2 now lives in the HIGH 16 bits of adjw words [WHT_OFF, WHT_OFF + 4M).
// bit0 (the adj mask) of every word is preserved; writes are idempotent RMW.
#define WHT_OFF (2 * NTOK)
static constexpr float LOG2E = 1.44269504088896f;

// ---------------------------------------------------------------------------
// dtype detector (bf16-packed vs fp32). Wave-uniform. Proven rounds 3-7.
// ---------------------------------------------------------------------------
__device__ __forceinline__ int detect_bf16(const void* h) {
    const unsigned* hw = (const unsigned*)h;
    unsigned w = hw[threadIdx.x & 63];
    unsigned ex = (w >> 7) & 0xFFu;
    unsigned long long b = __ballot(ex > 100u && ex < 150u);
    return __popcll(b) >= 40;
}

__device__ __forceinline__ float ldf(const void* p, int i, int isb) {
    return isb ? (float)((const bf16*)p)[i] : ((const float*)p)[i];
}

__device__ __forceinline__ bf16x8 cvt8(const float* p) {
    float4 a = *(const float4*)p;
    float4 b = *(const float4*)(p + 4);
    bf16x8 r;
    r[0]=(bf16)a.x; r[1]=(bf16)a.y; r[2]=(bf16)a.z; r[3]=(bf16)a.w;
    r[4]=(bf16)b.x; r[5]=(bf16)b.y; r[6]=(bf16)b.z; r[7]=(bf16)b.w;
    return r;
}

// WhT2 tiled layout: elem index for (b, f, n):
//   tile = b*32 + (n>>6); within tile: row f (64 elems), phys slot
//   ((n>>3)&7) ^ (f&7)  (XOR swizzle BAKED IN), byte elem n&7.
__device__ __forceinline__ size_t wht2_idx(int b, int f, int n) {
    int jc = n >> 6;
    int slot = ((n >> 3) & 7) ^ (f & 7);
    return (((size_t)(b * 32 + jc) * F_ + f) << 6) + (slot << 3) + (n & 7);
}

// ---------------------------------------------------------------------------
// Kernel A (fused s/t): WhT2 -> high halves of adjw words (WHT_OFF+idx);
// s,t stashed f16 in high halves of adjw[token] (t) and adjw[NTOK+token] (s).
// Mask bits preserved everywhere. ZERO workspace use.
// ---------------------------------------------------------------------------
__global__ __launch_bounds__(256)
void k_wht(const void* __restrict__ hv, const void* __restrict__ Wv,
           const void* __restrict__ Wbv, const void* __restrict__ ai_wv,
           const void* __restrict__ ai_bv, const void* __restrict__ aj_wv,
           const void* __restrict__ aj_bv, unsigned* __restrict__ adjw) {
    int isb = detect_bf16(hv);
    int ttile = blockIdx.x;            // 1024 token-tiles of 16
    int fg = threadIdx.x >> 6;         // 4 f-groups of 64
    int lane = threadIdx.x & 63;
    int T0 = ttile * 16;
    int m = lane & 15, quad = lane >> 4;

    f32x4 acc[4];
#pragma unroll
    for (int ft = 0; ft < 4; ++ft) acc[ft] = (f32x4){0.f, 0.f, 0.f, 0.f};

    if (isb) {
        const bf16* hp = (const bf16*)hv + (size_t)(T0 + m) * F_ + quad * 8;
        const bf16* wp = (const bf16*)Wv + (size_t)(fg * 64 + m) * F_ + quad * 8;
#pragma unroll
        for (int kk = 0; kk < F_; kk += 32) {
            bf16x8 hf = *(const bf16x8*)(hp + kk);
#pragma unroll
            for (int ft = 0; ft < 4; ++ft) {
                bf16x8 wf = *(const bf16x8*)(wp + (size_t)ft * 16 * F_ + kk);
                acc[ft] = __builtin_amdgcn_mfma_f32_16x16x32_bf16(wf, hf, acc[ft], 0, 0, 0);
            }
        }
    } else {
        const float* hp = (const float*)hv + (size_t)(T0 + m) * F_ + quad * 8;
        const float* wp = (const float*)Wv + (size_t)(fg * 64 + m) * F_ + quad * 8;
#pragma unroll
        for (int kk = 0; kk < F_; kk += 32) {
            bf16x8 hf = cvt8(hp + kk);
#pragma unroll
            for (int ft = 0; ft < 4; ++ft) {
                bf16x8 wf = cvt8(wp + (size_t)ft * 16 * F_ + kk);
                acc[ft] = __builtin_amdgcn_mfma_f32_16x16x32_bf16(wf, hf, acc[ft], 0, 0, 0);
            }
        }
    }
    int token = T0 + m;
    int b = token >> 11, n = token & (N_ - 1);
    unsigned* wbase = adjw + WHT_OFF;
    float s_p = 0.f, t_p = 0.f;
#pragma unroll
    for (int ft = 0; ft < 4; ++ft)
#pragma unroll
        for (int r = 0; r < 4; ++r) {
            int f = fg * 64 + ft * 16 + quad * 4 + r;
            float v = acc[ft][r] + ldf(Wbv, f, isb);
            bf16 vb = (bf16)v;
            unsigned short ub;
            __builtin_memcpy(&ub, &vb, 2);
            size_t widx = wht2_idx(b, f, n);
            unsigned ow = wbase[widx];                       // idempotent RMW
            wbase[widx] = (ow & 0xFFFFu) | ((unsigned)ub << 16);
            float vr = (float)vb;                    // rounded, matches stash
            s_p += vr * ldf(ai_wv, f, isb);
            t_p += vr * ldf(aj_wv, f, isb);
        }
    s_p += __shfl_down(s_p, 32, 64); s_p += __shfl_down(s_p, 16, 64);
    t_p += __shfl_down(t_p, 32, 64); t_p += __shfl_down(t_p, 16, 64);
    __shared__ float sred[4][16], tred[4][16];
    if (lane < 16) { sred[fg][lane] = s_p; tred[fg][lane] = t_p; }
    __syncthreads();
    if (threadIdx.x < 16) {
        int tid = threadIdx.x;
        int tok = T0 + tid;
        float ss = (sred[0][tid] + sred[1][tid] + sred[2][tid] + sred[3][tid]
                    + ldf(ai_bv, 0, isb)) * LOG2E;
        float tt = (tred[0][tid] + tred[1][tid] + tred[2][tid] + tred[3][tid]
                    + ldf(aj_bv, 0, isb)) * LOG2E;
        f16 th = (f16)tt, sh = (f16)ss;
        unsigned short tu, su;
        __builtin_memcpy(&tu, &th, 2);
        __builtin_memcpy(&su, &sh, 2);
        unsigned w0 = adjw[tok];
        adjw[tok] = (w0 & 0xFFFFu) | ((unsigned)tu << 16);
        unsigned w1 = adjw[NTOK + tok];
        adjw[NTOK + tok] = (w1 & 0xFFFFu) | ((unsigned)su << 16);
    }
}

__device__ __forceinline__ unsigned char pbits(uint4 a, uint4 b) {
    return (unsigned char)((a.x & 1u) | ((a.y & 1u) << 1) | ((a.z & 1u) << 2) |
                           ((a.w & 1u) << 3) | ((b.x & 1u) << 4) |
                           ((b.y & 1u) << 5) | ((b.z & 1u) << 6) |
                           ((b.w & 1u) << 7));
}

// reg-staged B chunk: load 8 adjw words (2x uint4), pack high halves with
// v_perm, ds_write_b128. Same LDS layout as the old global_load_lds path.
#define LDB(rr, xa, xb) do {                                                   \
    const uint4* _p = (const uint4*)(bwn + ((w * 8 + (rr)) * 512 + lane * 8)); \
    xa = _p[0]; xb = _p[1]; } while (0)
#define WRB(rr, xa, xb, dst) do {                                              \
    unsigned _d0 = __builtin_amdgcn_perm(xa.y, xa.x, 0x07060302u);             \
    unsigned _d1 = __builtin_amdgcn_perm(xa.w, xa.z, 0x07060302u);             \
    unsigned _d2 = __builtin_amdgcn_perm(xb.y, xb.x, 0x07060302u);             \
    unsigned _d3 = __builtin_amdgcn_perm(xb.w, xb.z, 0x07060302u);             \
    *(uint4*)((dst) + (w * 8 + (rr)) * 1024 + lane * 16) =                     \
        (uint4){_d0, _d1, _d2, _d3}; } while (0)

// ---------------------------------------------------------------------------
// Kernel C: fused masked-softmax attention + PV + ELU. R=32 rows/block,
// 512 blocks (2/CU) x 256 thr (4 waves = 2 m-tiles x 2 j-halves).
// j in 32 chunks of 64: B tile reg-staged from adjw high halves (dbuf);
// adj bit-packed to LDS (dbuf); l via all-ones MFMA. One barrier per chunk.
// ---------------------------------------------------------------------------
__global__ __launch_bounds__(256)
void k_attn(const unsigned* __restrict__ adjw,
            const void* __restrict__ hv, void* __restrict__ outv) {
    int isb = detect_bf16(hv);
    int bid = blockIdx.x;
    int b = bid >> 6, itile = bid & 63, i0 = itile * 32;
    int tid = threadIdx.x;
    int w = tid >> 6, lane = tid & 63, m = lane & 15, q = lane >> 4;
    int mt = w >> 1, jh = w & 1;

    __shared__ __align__(16) char smem[70656];
    char* Bbuf0 = smem;                                    // 32 KB
    char* Bbuf1 = smem + 32768;                            // 32 KB
    f16* tLDS   = (f16*)(smem + 65536);                    // 4 KB
    unsigned char* pack0 = (unsigned char*)(smem + 69632); // 256 B
    unsigned char* pack1 = (unsigned char*)(smem + 69888); // 256 B
    float* red  = (float*)smem;           // epilogue overlay [32][257]

    const unsigned* batch_words = adjw + WHT_OFF + (size_t)b * 32 * F_ * 64;

    // ---- prologue ----
#pragma unroll
    for (int k = 0; k < 8; ++k) {
        int idx = k * 256 + tid;
        unsigned wv = adjw[b * N_ + idx];
        unsigned short us = (unsigned short)(wv >> 16);
        f16 tv; __builtin_memcpy(&tv, &us, 2);
        tLDS[idx] = tv;
    }
    int row = i0 + mt * 16 + m;
    unsigned swd = adjw[NTOK + b * N_ + row];
    unsigned short su = (unsigned short)(swd >> 16);
    f16 sh; __builtin_memcpy(&sh, &su, 2);
    float s2i = (float)sh;

    int prow = tid >> 3, ps = tid & 7;         // 32 rows x 8 bytes
    const unsigned* arow = adjw + ((size_t)(b * N_ + i0 + prow)) * N_ + ps * 8;
    {
        uint4 x0 = *(const uint4*)arow, x1 = *(const uint4*)(arow + 4);
        pack0[prow * 8 + ps] = pbits(x0, x1);
    }
    {   // stage chunk 0 into Bbuf0
        const unsigned* bwn = batch_words;
#pragma unroll
        for (int r = 0; r < 8; ++r) {
            uint4 xa, xb;
            LDB(r, xa, xb);
            WRB(r, xa, xb, Bbuf0);
        }
    }
    __syncthreads();

    bf16x8 ones;
#pragma unroll
    for (int k = 0; k < 8; ++k) ones[k] = (bf16)1.0f;

    f32x4 acc[16];
#pragma unroll
    for (int ft = 0; ft < 16; ++ft) acc[ft] = (f32x4){0.f, 0.f, 0.f, 0.f};
    f32x4 acc_l = {0.f, 0.f, 0.f, 0.f};

    for (int c = 0; c < 32; ++c) {
        char* Bcur = (c & 1) ? Bbuf1 : Bbuf0;
        char* Bnxt = (c & 1) ? Bbuf0 : Bbuf1;
        unsigned char* pcur = (c & 1) ? pack1 : pack0;
        bool pre = (c < 31);
        const unsigned* bwn = batch_words + (size_t)(c + 1) * (F_ * 64);
        uint4 xa0, xb0, xa1, xb1, xa2, xb2, xa3, xb3;
        uint4 aw0, aw1;
        if (pre) {
            LDB(0, xa0, xb0); LDB(1, xa1, xb1);
            LDB(2, xa2, xb2); LDB(3, xa3, xb3);
            aw0 = *(const uint4*)(arow + (size_t)(c + 1) * 64);
            aw1 = *(const uint4*)(arow + (size_t)(c + 1) * 64 + 4);
        }
        // ---- compute chunk c ----
        unsigned long long pb64 =
            *(const unsigned long long*)(pcur + (mt * 16 + m) * 8);
        unsigned bits8 = (unsigned)(pb64 >> ((jh * 4 + q) * 8)) & 0xFFu;
        f16x8 tv = *(const f16x8*)(tLDS + c * 64 + jh * 32 + q * 8);

        bf16x8 af;
#pragma unroll
        for (int qq = 0; qq < 8; ++qq) {
            float x = s2i + (float)tv[qq];
            x = fmaxf(x, 0.2f * x);                    // LeakyReLU (log2-scaled)
            float pv = ((bits8 >> qq) & 1u) ? __builtin_amdgcn_exp2f(x) : 0.f;
            af[qq] = (bf16)pv;
        }
        int sbase = (jh * 4 + q);                      // logical slot
#pragma unroll
        for (int ft = 0; ft < 8; ++ft) {
            int fr = ft * 16 + m;
            int psl = sbase ^ (m & 7);                 // phys slot (pre-baked)
            bf16x8 bfr = *(const bf16x8*)(Bcur + fr * 128 + psl * 16);
            acc[ft] = __builtin_amdgcn_mfma_f32_16x16x32_bf16(af, bfr, acc[ft], 0, 0, 0);
        }
        if (pre) {     // drain first half of next-chunk loads, issue second
            WRB(0, xa0, xb0, Bnxt); WRB(1, xa1, xb1, Bnxt);
            WRB(2, xa2, xb2, Bnxt); WRB(3, xa3, xb3, Bnxt);
            LDB(4, xa0, xb0); LDB(5, xa1, xb1);
            LDB(6, xa2, xb2); LDB(7, xa3, xb3);
        }
#pragma unroll
        for (int ft = 8; ft < 16; ++ft) {
            int fr = ft * 16 + m;
            int psl = sbase ^ (m & 7);
            bf16x8 bfr = *(const bf16x8*)(Bcur + fr * 128 + psl * 16);
            acc[ft] = __builtin_amdgcn_mfma_f32_16x16x32_bf16(af, bfr, acc[ft], 0, 0, 0);
        }
        acc_l = __builtin_amdgcn_mfma_f32_16x16x32_bf16(af, ones, acc_l, 0, 0, 0);
        if (pre) {
            WRB(4, xa0, xb0, Bnxt); WRB(5, xa1, xb1, Bnxt);
            WRB(6, xa2, xb2, Bnxt); WRB(7, xa3, xb3, Bnxt);
            ((c & 1) ? pack0 : pack1)[prow * 8 + ps] = pbits(aw0, aw1);
        }
        __syncthreads();
    }

    // ---- epilogue: cross-jh reduce via LDS overlay ----
    if (jh == 1) {
#pragma unroll
        for (int r = 0; r < 4; ++r) {
            int rr = mt * 16 + q * 4 + r;
#pragma unroll
            for (int ft = 0; ft < 16; ++ft)
                red[rr * 257 + ft * 16 + m] = acc[ft][r];
            if (m == 0) red[rr * 257 + 256] = acc_l[r];
        }
    }
    __syncthreads();
    if (jh == 0) {
#pragma unroll
        for (int r = 0; r < 4; ++r) {
            int rr = mt * 16 + q * 4 + r;
            float lf = acc_l[r] + red[rr * 257 + 256];
            float rl = (lf > 0.f) ? (1.f / lf) : 0.f;
            size_t ob = ((size_t)b * N_ + i0 + rr) * F_;
#pragma unroll
            for (int ft = 0; ft < 16; ++ft) {
                int f = ft * 16 + m;
                float v = acc[ft][r] + red[rr * 257 + f];
                v *= rl;
                v = (v > 0.f) ? v : (__builtin_amdgcn_exp2f(v * LOG2E) - 1.f);
                if (isb) ((bf16*)outv)[ob + f] = (bf16)v;
                else     ((float*)outv)[ob + f] = v;
            }
        }
    }
}

// ---------------------------------------------------------------------------
extern "C" void kernel_launch(void* const* d_in, const int* in_sizes, int n_in,
                              void* d_out, int out_size, void* d_ws, size_t ws_size,
                              hipStream_t stream) {
    (void)in_sizes; (void)n_in; (void)out_size; (void)d_ws; (void)ws_size;
    const void* h    = d_in[0];
    unsigned*   adjw = (unsigned*)d_in[1];   // int32 adj; high 16 bits reused
    const void* W_w  = d_in[2];
    const void* W_b  = d_in[3];
    const void* ai_w = d_in[4];
    const void* ai_b = d_in[5];
    const void* aj_w = d_in[6];
    const void* aj_b = d_in[7];

    // ZERO workspace use: WhT2 lives in adjw high halves.
    k_wht <<<dim3(1024), dim3(256), 0, stream>>>(h, W_w, W_b, ai_w, ai_b,
                                                 aj_w, aj_b, adjw);
    k_attn<<<dim3(512),  dim3(256), 0, stream>>>(adjw, h, d_out);
}